// Round 2
// baseline (247.799 us; speedup 1.0000x reference)
//
#include <hip/hip_runtime.h>

typedef _Float16 half8 __attribute__((ext_vector_type(8)));
typedef _Float16 half4 __attribute__((ext_vector_type(4)));
typedef float f32x4 __attribute__((ext_vector_type(4)));

#define TT 512
#define HH 64
#define MB 4      // real batches per block -> 512 blocks -> 2 blocks/CU (antiphase overlap)
#define S  88     // state row stride (halfs): 176B rows -> wave h-writes hit 32 distinct banks
#define XS 2056   // xbuf per-batch stride (halfs): 512*4 + 8 pad (pad absorbs t=TT prefetch)

__global__ __launch_bounds__(256, 2)
void lstm_v13(const float* __restrict__ x,
              const float* __restrict__ W_ih,
              const float* __restrict__ W_hh,
              const float* __restrict__ b_ih,
              const float* __restrict__ b_hh,
              const float* __restrict__ W_fc,
              const float* __restrict__ b_fc,
              float* __restrict__ out)
{
    __shared__ __align__(16) _Float16 st[2][MB * S];     // 1408 B: h state, dbuf
    __shared__ __align__(16) _Float16 xbuf[MB * XS];     // 16448 B: ALL x, staged once

    const int tid = threadIdx.x;
    const int w   = tid >> 6;      // wave 0..3
    const int l   = tid & 63;
    const int q   = l >> 4;
    const int col = l & 15;
    const int bt  = col & 3;       // batch within block (4 replica col-groups)
    const int g   = col >> 2;      // replica group -> acc selector
    const int b0  = blockIdx.x * MB;

    const float kN = -1.4426950408889634f;   // -log2(e)
    const float kP =  2.8853900817779268f;   // +2*log2(e)

    // ---- persistent A fragments: 4 tiles per wave, units 16w+4p+q ----
    // tile p row m: gate-row r(m) = 64*(m&3) + 16w + 4p + (m>>2)
    // => C: lane (q,col) reg j = gate j of unit 16w+4p+q  (batch col&3)
    // Weights PRESCALED by exp2 constants (f32 mul BEFORE f16 cvt: single rounding).
    half8 aw[4][3];
    #pragma unroll
    for (int p = 0; p < 4; ++p) {
        const int r = 64 * (col & 3) + 16 * w + 4 * p + (col >> 2);
        const float scale = ((col & 3) == 2) ? kP : kN;   // gate g -> kP, i/f/o -> kN
        #pragma unroll
        for (int c = 0; c < 2; ++c) {
            const float* src = W_hh + r * HH + 32 * c + 8 * q;
            half8 v;
            #pragma unroll
            for (int j = 0; j < 8; ++j) v[j] = (_Float16)(src[j] * scale);
            aw[p][c] = v;
        }
        half8 v = {};
        if (q == 0) {   // k=64..67 -> W_ih, k=68 -> bias (B supplies 1.0 at k=68)
            #pragma unroll
            for (int j = 0; j < 4; ++j) v[j] = (_Float16)(W_ih[r * 4 + j] * scale);
            v[4] = (_Float16)((b_ih[r] + b_hh[r]) * scale);
        }
        aw[p][2] = v;
    }

    // ---- pre-stage ALL x for this block's 4 batches into LDS (f16) ----
    #pragma unroll
    for (int it = 0; it < (MB * TT) / 256; ++it) {
        const int task = tid + it * 256;
        const int b = task >> 9, t = task & 511;
        float4 v = *(const float4*)(x + ((size_t)(b0 + b) * TT + t) * 4);
        half4 hx;
        hx[0] = (_Float16)v.x; hx[1] = (_Float16)v.y;
        hx[2] = (_Float16)v.z; hx[3] = (_Float16)v.w;
        *(half4*)&xbuf[b * XS + t * 4] = hx;
    }

    // ---- zero h state (both buffers) ----
    for (int i = tid; i < 2 * MB * S; i += 256) (&st[0][0])[i] = (_Float16)0.f;
    __syncthreads();

    float cs = 0.f;                // cell state: unit 16w+4g+q, batch bt
    const int wrow = bt * S + 16 * w + 4 * g + q;   // loop-invariant h-write addr
    const _Float16 hone = (_Float16)1.0f, hzer = (_Float16)0.f;
    const f32x4 z4 = {0.f, 0.f, 0.f, 0.f};
    const bool s1 = (g & 1) != 0, s2 = (g & 2) != 0;

    // prologue: x/bias MFMAs for t=0
    f32x4 accx0, accx1, accx2, accx3;
    {
        half4 xv = *(const half4*)&xbuf[bt * XS + 0];
        half8 bx = {xv[0], xv[1], xv[2], xv[3], hone, hzer, hzer, hzer};
        accx0 = __builtin_amdgcn_mfma_f32_16x16x32_f16(aw[0][2], bx, z4, 0, 0, 0);
        accx1 = __builtin_amdgcn_mfma_f32_16x16x32_f16(aw[1][2], bx, z4, 0, 0, 0);
        accx2 = __builtin_amdgcn_mfma_f32_16x16x32_f16(aw[2][2], bx, z4, 0, 0, 0);
        accx3 = __builtin_amdgcn_mfma_f32_16x16x32_f16(aw[3][2], bx, z4, 0, 0, 0);
    }

    #pragma unroll 4
    for (int t = 0; t < TT; ++t) {
        const int rb = t & 1, wb = rb ^ 1;
        const _Float16* sr = &st[rb][0];

        // broadcast reads: 4 replica col-groups read the same address (free)
        half8 bh0 = *(const half8*)&sr[bt * S +      8 * q];   // k 0..31
        half8 bh1 = *(const half8*)&sr[bt * S + 32 + 8 * q];   // k 32..63
        half4 xv2 = *(const half4*)&xbuf[bt * XS + (t + 1) * 4]; // prefetch (pad-safe)

        // h-MFMAs: chain depth 2 (x/bias contribution precomputed last iter)
        f32x4 a0 = __builtin_amdgcn_mfma_f32_16x16x32_f16(aw[0][0], bh0, accx0, 0, 0, 0);
        f32x4 a1 = __builtin_amdgcn_mfma_f32_16x16x32_f16(aw[1][0], bh0, accx1, 0, 0, 0);
        f32x4 a2 = __builtin_amdgcn_mfma_f32_16x16x32_f16(aw[2][0], bh0, accx2, 0, 0, 0);
        f32x4 a3 = __builtin_amdgcn_mfma_f32_16x16x32_f16(aw[3][0], bh0, accx3, 0, 0, 0);
        a0 = __builtin_amdgcn_mfma_f32_16x16x32_f16(aw[0][1], bh1, a0, 0, 0, 0);
        a1 = __builtin_amdgcn_mfma_f32_16x16x32_f16(aw[1][1], bh1, a1, 0, 0, 0);
        a2 = __builtin_amdgcn_mfma_f32_16x16x32_f16(aw[2][1], bh1, a2, 0, 0, 0);
        a3 = __builtin_amdgcn_mfma_f32_16x16x32_f16(aw[3][1], bh1, a3, 0, 0, 0);

        // x/bias MFMAs for t+1, independent of this step's h
        {
            half8 bx2 = {xv2[0], xv2[1], xv2[2], xv2[3], hone, hzer, hzer, hzer};
            accx0 = __builtin_amdgcn_mfma_f32_16x16x32_f16(aw[0][2], bx2, z4, 0, 0, 0);
            accx1 = __builtin_amdgcn_mfma_f32_16x16x32_f16(aw[1][2], bx2, z4, 0, 0, 0);
            accx2 = __builtin_amdgcn_mfma_f32_16x16x32_f16(aw[2][2], bx2, z4, 0, 0, 0);
            accx3 = __builtin_amdgcn_mfma_f32_16x16x32_f16(aw[3][2], bx2, z4, 0, 0, 0);
        }

        // ---- select this lane's unit: acc[col>>2] (cndmask tree, no cross-lane) ----
        #define SEL(j) (s2 ? (s1 ? a3[j] : a2[j]) : (s1 ? a1[j] : a0[j]))
        const float gi = SEL(0);   // prescaled by kN
        const float gf = SEL(1);   // prescaled by kN
        const float gg = SEL(2);   // prescaled by kP
        const float go = SEL(3);   // prescaled by kN
        #undef SEL

        const float EI = __builtin_amdgcn_exp2f(gi);
        const float EF = __builtin_amdgcn_exp2f(gf);
        const float EG = __builtin_amdgcn_exp2f(gg);
        const float rF = __builtin_amdgcn_rcpf(1.f + EF);
        const float r1 = __builtin_amdgcn_rcpf((1.f + EI) * (EG + 1.f));
        cs = cs * rF + (EG - 1.f) * r1;
        const float EO = __builtin_amdgcn_exp2f(go);
        const float EC = __builtin_amdgcn_exp2f(kP * cs);
        const float r2 = __builtin_amdgcn_rcpf((1.f + EO) * (EC + 1.f));
        const float hn = (EC - 1.f) * r2;

        st[wb][wrow] = (_Float16)hn;    // wave's 64 writes hit 32 distinct banks, 2B halves
        __syncthreads();
    }

    // ---- FC epilogue: final h in st[0] (TT even) ----
    if (tid < MB * 4) {
        const int b = tid >> 2, o = tid & 3;
        float s = b_fc[o];
        const float* wf = W_fc + o * HH;
        #pragma unroll
        for (int k = 0; k < HH; ++k)
            s = fmaf((float)st[0][b * S + k], wf[k], s);
        out[(size_t)(b0 + b) * 4 + o] = s;
    }
}

extern "C" void kernel_launch(void* const* d_in, const int* in_sizes, int n_in,
                              void* d_out, int out_size, void* d_ws, size_t ws_size,
                              hipStream_t stream) {
    const float* x    = (const float*)d_in[0];
    const float* W_ih = (const float*)d_in[1];
    const float* W_hh = (const float*)d_in[2];
    const float* b_ih = (const float*)d_in[3];
    const float* b_hh = (const float*)d_in[4];
    const float* W_fc = (const float*)d_in[5];
    const float* b_fc = (const float*)d_in[6];
    float* out = (float*)d_out;
    lstm_v13<<<2048 / MB, 256, 0, stream>>>(x, W_ih, W_hh, b_ih, b_hh, W_fc, b_fc, out);
}

// Round 3
// 247.665 us; speedup vs baseline: 1.0005x; 1.0005x over previous
//
#include <hip/hip_runtime.h>

typedef _Float16 half8 __attribute__((ext_vector_type(8)));
typedef _Float16 half4 __attribute__((ext_vector_type(4)));
typedef float f32x4 __attribute__((ext_vector_type(4)));

#define TT 512
#define HH 64
#define MB 8      // batches per block -> 256 blocks, 1024 thr: 16 waves/CU = 4/SIMD
#define S  80     // state row stride (halfs): 160B rows -> reads/writes max 2-way banks (free)
#define XS 2056   // xbuf per-batch stride (halfs): 512*4 + 8 pad (pad absorbs t=TT prefetch)

__global__ __launch_bounds__(1024, 1)
void lstm_v14(const float* __restrict__ x,
              const float* __restrict__ W_ih,
              const float* __restrict__ W_hh,
              const float* __restrict__ b_ih,
              const float* __restrict__ b_hh,
              const float* __restrict__ W_fc,
              const float* __restrict__ b_fc,
              float* __restrict__ out)
{
    __shared__ __align__(16) _Float16 st[2][MB * S];     // 2560 B: h state, dbuf
    __shared__ __align__(16) _Float16 xbuf[MB * XS];     // 32896 B: ALL x, staged once

    const int tid = threadIdx.x;
    const int w   = tid >> 6;      // wave 0..15
    const int l   = tid & 63;
    const int q   = l >> 4;
    const int col = l & 15;
    const int bt  = col & 7;       // batch within block (cols 8..15 are x2 duplicates)
    const int b0  = blockIdx.x * MB;

    const float kN = -1.4426950408889634f;   // -log2(e)
    const float kP =  2.8853900817779268f;   // +2*log2(e)

    // ---- persistent A fragments: ONE tile per wave, units 4w+q ----
    // C-row m = 4*q_row + j  ->  gate-row r(m) = 64*(m&3) + 4w + (m>>2)
    // => C: lane (q,col) reg j = gate j of unit u = 4w + q   (batch col&7)
    // A-frag row for lane (q,col): substitute (q_row,j) = (col>>2, col&3).
    // Weights PRESCALED by exp2 constants (f32 mul BEFORE f16 cvt: single rounding).
    half8 aw[3];
    {
        const int r = 64 * (col & 3) + 4 * w + (col >> 2);
        const float scale = ((col & 3) == 2) ? kP : kN;   // gate g -> kP, i/f/o -> kN
        #pragma unroll
        for (int c = 0; c < 2; ++c) {
            const float* src = W_hh + r * HH + 32 * c + 8 * q;
            half8 v;
            #pragma unroll
            for (int j = 0; j < 8; ++j) v[j] = (_Float16)(src[j] * scale);
            aw[c] = v;
        }
        half8 v = {};
        if (q == 0) {   // k=64..67 -> W_ih, k=68 -> bias (B supplies 1.0 at k=68)
            #pragma unroll
            for (int j = 0; j < 4; ++j) v[j] = (_Float16)(W_ih[r * 4 + j] * scale);
            v[4] = (_Float16)((b_ih[r] + b_hh[r]) * scale);
        }
        aw[2] = v;
    }

    // ---- pre-stage ALL x for this block's 8 batches into LDS (f16) ----
    #pragma unroll
    for (int it = 0; it < (MB * TT) / 1024; ++it) {
        const int task = tid + it * 1024;
        const int b = task >> 9, t = task & 511;
        float4 v = *(const float4*)(x + ((size_t)(b0 + b) * TT + t) * 4);
        half4 hx;
        hx[0] = (_Float16)v.x; hx[1] = (_Float16)v.y;
        hx[2] = (_Float16)v.z; hx[3] = (_Float16)v.w;
        *(half4*)&xbuf[b * XS + t * 4] = hx;
    }

    // ---- zero h state (both buffers) ----
    for (int i = tid; i < 2 * MB * S; i += 1024) (&st[0][0])[i] = (_Float16)0.f;
    __syncthreads();

    float cs = 0.f;                // cell state: unit 4w+q, batch bt
    const int wrow = bt * S + 4 * w + q;     // loop-invariant h-write addr (col<8 writes)
    const bool writer = (col < 8);
    const _Float16 hone = (_Float16)1.0f, hzer = (_Float16)0.f;
    const f32x4 z4 = {0.f, 0.f, 0.f, 0.f};

    // prologue: x/bias MFMA for t=0
    f32x4 accx;
    {
        half4 xv = *(const half4*)&xbuf[bt * XS + 0];
        half8 bx = {xv[0], xv[1], xv[2], xv[3], hone, hzer, hzer, hzer};
        accx = __builtin_amdgcn_mfma_f32_16x16x32_f16(aw[2], bx, z4, 0, 0, 0);
    }

    #pragma unroll 4
    for (int t = 0; t < TT; ++t) {
        const int rb = t & 1, wb = rb ^ 1;
        const _Float16* sr = &st[rb][0];

        // broadcast reads: dup col-groups read the same address (free); 2-way banks (free)
        half8 bh0 = *(const half8*)&sr[bt * S +      8 * q];   // k 0..31
        half8 bh1 = *(const half8*)&sr[bt * S + 32 + 8 * q];   // k 32..63
        half4 xv2 = *(const half4*)&xbuf[bt * XS + (t + 1) * 4]; // prefetch (pad-safe)

        // h-MFMAs: chain depth 2 (x/bias contribution precomputed last iter)
        f32x4 a0 = __builtin_amdgcn_mfma_f32_16x16x32_f16(aw[0], bh0, accx, 0, 0, 0);
        a0 = __builtin_amdgcn_mfma_f32_16x16x32_f16(aw[1], bh1, a0, 0, 0, 0);

        // x/bias MFMA for t+1, independent of this step's h
        {
            half8 bx2 = {xv2[0], xv2[1], xv2[2], xv2[3], hone, hzer, hzer, hzer};
            accx = __builtin_amdgcn_mfma_f32_16x16x32_f16(aw[2], bx2, z4, 0, 0, 0);
        }

        // ---- every lane: full update for (unit 4w+q, batch col&7); cols 8-15 redundant ----
        const float gi = a0[0];   // prescaled by kN
        const float gf = a0[1];   // prescaled by kN
        const float gg = a0[2];   // prescaled by kP
        const float go = a0[3];   // prescaled by kN

        const float EI = __builtin_amdgcn_exp2f(gi);
        const float EF = __builtin_amdgcn_exp2f(gf);
        const float EG = __builtin_amdgcn_exp2f(gg);
        const float rF = __builtin_amdgcn_rcpf(1.f + EF);
        const float r1 = __builtin_amdgcn_rcpf((1.f + EI) * (EG + 1.f));
        cs = cs * rF + (EG - 1.f) * r1;
        const float EO = __builtin_amdgcn_exp2f(go);
        const float EC = __builtin_amdgcn_exp2f(kP * cs);
        const float r2 = __builtin_amdgcn_rcpf((1.f + EO) * (EC + 1.f));
        const float hn = (EC - 1.f) * r2;

        if (writer) st[wb][wrow] = (_Float16)hn;   // 2B; 2 lanes/bank max = free
        __syncthreads();
    }

    // ---- FC epilogue: final h in st[0] (TT even) ----
    if (tid < MB * 4) {
        const int b = tid >> 2, o = tid & 3;
        float s = b_fc[o];
        const float* wf = W_fc + o * HH;
        #pragma unroll
        for (int k = 0; k < HH; ++k)
            s = fmaf((float)st[0][b * S + k], wf[k], s);
        out[(size_t)(b0 + b) * 4 + o] = s;
    }
}

extern "C" void kernel_launch(void* const* d_in, const int* in_sizes, int n_in,
                              void* d_out, int out_size, void* d_ws, size_t ws_size,
                              hipStream_t stream) {
    const float* x    = (const float*)d_in[0];
    const float* W_ih = (const float*)d_in[1];
    const float* W_hh = (const float*)d_in[2];
    const float* b_ih = (const float*)d_in[3];
    const float* b_hh = (const float*)d_in[4];
    const float* W_fc = (const float*)d_in[5];
    const float* b_fc = (const float*)d_in[6];
    float* out = (float*)d_out;
    lstm_v14<<<2048 / MB, 1024, 0, stream>>>(x, W_ih, W_hh, b_ih, b_hh, W_fc, b_fc, out);
}